// Round 10
// baseline (1732.765 us; speedup 1.0000x reference)
//
#include <hip/hip_runtime.h>

#define B_ 512
#define L_ 1000
#define H_ 128
#define G_ 512  // 4*H

typedef _Float16 v8h __attribute__((ext_vector_type(8)));
typedef _Float16 h2t __attribute__((ext_vector_type(2)));
typedef float v4f __attribute__((ext_vector_type(4)));

__device__ __forceinline__ float sigmoid_f(float x) {
  return __builtin_amdgcn_rcpf(1.0f + __builtin_amdgcn_exp2f(-1.4426950408889634f * x));
}
__device__ __forceinline__ float tanh_f(float x) {
  return 1.0f - 2.0f * __builtin_amdgcn_rcpf(1.0f + __builtin_amdgcn_exp2f(2.8853900817779268f * x));
}

// h storage in B-FRAGMENT ORDER: chunk (kt, quad, row) at byte offset
// kt*144 + quad*32 + row*16 holds h_row[kt*32 + quad*8 + j], j=0..7 (f16).
// C-read (per kt): quad*32 + (m15&1)*16 -> 8 distinct addrs, one per
// bank-group -> pure broadcast, zero conflicts. U-write: one dword/lane,
// max 2 lanes/bank = free (m136). kt stride 144 destaggers kt blocks.
#define FB_KT 144

#define MFMA16(a, b, c) __builtin_amdgcn_mfma_f32_16x16x32_f16((a), (b), (c), 0, 0, 0)

// ROUND-9: LEAN-8-STAGGER. LEAN-8 (1604us, MfmaUtil 40%) confirmed burst
// overhead scales with wave count. Refined model: one 16x16x32 f16 MFMA =
// ~20 cy PER MATRIX UNIT (2075TF / 1024 units), so 96 MFMA/SIMD/step =
// 1920 cy = 44% of the 4365-cy step; the rest is SegU (matrix pipe parked
// ~500cy) + ds-burst + 2 barrier drains. Floor ~825us. This round overlaps
// U under MFMA via the round-6 layer-stagger (audited+ran correct) at 8
// waves -- clean A/B vs LEAN-8: same waves/fragments/U-code, only the
// C-burst is split across the two existing barriers:
//   SegA(t): U1(t) [wv0-1]   || all 8: gbuf2 = A2h@h2(t-2)+A2i@h1(t-1)
//            (32 MFMA/wave, 64/SIMD ~1320cy; U1 ~400cy hides fully)
//   SegB(t): U2(t-1) [wv2-3] || all 8: gbuf1 = A1@h1(t)
//            (16 MFMA/wave, 32/SIMD ~660cy; U2 hides fully)
// Deps (each crosses >=1 barrier; verified r6):
//   h1(t): SegA(t)[hb1[t&1]] -> C-B SegB(t) + C-A SegA(t+1) (parity t&1)
//   h2(t-1): SegB(t)[hb2] -> C-A SegA(t+1); C-A(t) reads hb2 BEFORE that write
//   gbuf2: SegA(t) -> U2(t-1) SegB(t);  gbuf1: SegB(t) -> U1(t+1) SegA(t+1)
// U2(tau) = A2i@h1(tau) + A2h@h2(tau-1) + bias, tau=t-1 == reference.
__global__ __launch_bounds__(512, 2) void lstm_mfma(
    const float* __restrict__ x,
    const float* __restrict__ w_ih1,
    const float* __restrict__ w_hh1,
    const float* __restrict__ b_ih1,
    const float* __restrict__ b_hh1,
    const float* __restrict__ w_ih2,
    const float* __restrict__ w_hh2,
    const float* __restrict__ b_ih2,
    const float* __restrict__ b_hh2,
    const float* __restrict__ w_lin,
    const float* __restrict__ b_lin,
    float* __restrict__ out)
{
  __shared__ __align__(16) float xlds[2][L_];        // block's 2 x-rows
  __shared__ __align__(16) float olds[2 * L_];       // staged outputs
  __shared__ __align__(16) float gbuf1[2][G_];       // [row] A1@h1 carry
  __shared__ __align__(16) float gbuf2[2][G_];       // [row] gates2 raw
  __shared__ __align__(16) unsigned char hb1[2][4 * FB_KT];  // [parity] h1 frag-order
  __shared__ __align__(16) unsigned char hb2[4 * FB_KT];     // h2 frag-order
  __shared__ __align__(16) float wxb[G_];            // w_ih1 column
  __shared__ __align__(16) float bbb1[G_];           // b_ih1+b_hh1
  __shared__ __align__(16) float bbb2[G_];           // b_ih2+b_hh2
  __shared__ __align__(16) float wlb[H_];            // w_lin row

  const int tid  = threadIdx.x;        // 0..511
  const int wv   = tid >> 6;           // 0..7
  const int lane = tid & 63;
  const int quad = lane >> 4;
  const int m15  = lane & 15;
  const int r0   = blockIdx.x * 2;
  const int e    = 2 * lane;

  // ---- one-time staging / zero-init (512 threads) ----
  for (int i = tid; i < 2 * L_; i += 512) ((float*)xlds)[i] = x[r0 * L_ + i];
  ((float*)gbuf1)[tid]       = 0.f;    // 1024 dwords total
  ((float*)gbuf1)[tid + 512] = 0.f;
  wxb[tid]  = w_ih1[tid];              // tid spans exactly G_
  bbb1[tid] = b_ih1[tid] + b_hh1[tid];
  bbb2[tid] = b_ih2[tid] + b_hh2[tid];
  if (tid < H_) wlb[tid] = w_lin[tid];
  if (tid < 288) ((unsigned*)hb1)[tid] = 0u;   // h1(-1)=0, both parities
  if (tid < 144) ((unsigned*)hb2)[tid] = 0u;   // h2(-1)=h2(-2)=0
  const float blv = b_lin[0];

  // ---- per-wave fragments: mtiles 4wv..4wv+3 of A1,A2i,A2h (192 dwords) ----
  v8h A1f[4][4], A2if[4][4], A2hf[4][4];
#pragma unroll
  for (int mt = 0; mt < 4; ++mt) {
    const int grow = ((4 * wv + mt) * 16 + m15) * H_;
#pragma unroll
    for (int kt = 0; kt < 4; ++kt) {
      const int koff = kt * 32 + quad * 8;
      float4 a, b;
      a = *(const float4*)(w_hh1 + grow + koff);
      b = *(const float4*)(w_hh1 + grow + koff + 4);
      A1f[mt][kt] = v8h{(_Float16)a.x, (_Float16)a.y, (_Float16)a.z, (_Float16)a.w,
                        (_Float16)b.x, (_Float16)b.y, (_Float16)b.z, (_Float16)b.w};
      a = *(const float4*)(w_ih2 + grow + koff);
      b = *(const float4*)(w_ih2 + grow + koff + 4);
      A2if[mt][kt] = v8h{(_Float16)a.x, (_Float16)a.y, (_Float16)a.z, (_Float16)a.w,
                         (_Float16)b.x, (_Float16)b.y, (_Float16)b.z, (_Float16)b.w};
      a = *(const float4*)(w_hh2 + grow + koff);
      b = *(const float4*)(w_hh2 + grow + koff + 4);
      A2hf[mt][kt] = v8h{(_Float16)a.x, (_Float16)a.y, (_Float16)a.z, (_Float16)a.w,
                         (_Float16)b.x, (_Float16)b.y, (_Float16)b.z, (_Float16)b.w};
    }
  }

  float c1x = 0.f, c1y = 0.f;  // layer-1 cell state (waves 0,1; row = wv)
  float c2x = 0.f, c2y = 0.f;  // layer-2 cell state (waves 2,3; row = wv-2)

  // U write offset: elements 2*lane,2*lane+1 -> byte kt*144 + quad'*32 + (l&3)*4
  const int hwo = (lane >> 4) * FB_KT + ((lane >> 2) & 3) * 32 + (lane & 3) * 4;
  const int roff = quad * 32 + (m15 & 1) * 16;

  __syncthreads();

  for (int t = 0; t <= L_; ++t) {
    // ===== SegA: U1(t) [wv0-1] || C-A: gbuf2 = A2h@h2(t-2)+A2i@h1(t-1) =====
    if (tid < 128 && t < L_) {
      const int row = tid >> 6;
      const float xv = xlds[row][t];
      const float* g1 = gbuf1[row];
      float2 gi = *(const float2*)&g1[e];
      float2 gf = *(const float2*)&g1[128 + e];
      float2 gg = *(const float2*)&g1[256 + e];
      float2 go = *(const float2*)&g1[384 + e];
      float2 wxi = *(const float2*)&wxb[e],       bi = *(const float2*)&bbb1[e];
      float2 wxf = *(const float2*)&wxb[128 + e], bf = *(const float2*)&bbb1[128 + e];
      float2 wxg = *(const float2*)&wxb[256 + e], bg = *(const float2*)&bbb1[256 + e];
      float2 wxo = *(const float2*)&wxb[384 + e], bo = *(const float2*)&bbb1[384 + e];
      float i0 = sigmoid_f(gi.x + wxi.x * xv + bi.x);
      float i1 = sigmoid_f(gi.y + wxi.y * xv + bi.y);
      float f0 = sigmoid_f(gf.x + wxf.x * xv + bf.x);
      float f1 = sigmoid_f(gf.y + wxf.y * xv + bf.y);
      float g0 = tanh_f(gg.x + wxg.x * xv + bg.x);
      float g1v = tanh_f(gg.y + wxg.y * xv + bg.y);
      float o0 = sigmoid_f(go.x + wxo.x * xv + bo.x);
      float o1 = sigmoid_f(go.y + wxo.y * xv + bo.y);
      c1x = f0 * c1x + i0 * g0;
      c1y = f1 * c1y + i1 * g1v;
      h2t hp = h2t{(_Float16)(o0 * tanh_f(c1x)), (_Float16)(o1 * tanh_f(c1y))};
      *(unsigned*)(&hb1[t & 1][0] + row * 16 + hwo) = __builtin_bit_cast(unsigned, hp);
    }
    {  // C-A: all 8 waves, 32 MFMA each (runs at t=L too: feeds U2(L-1))
      v4f a2[4];
#pragma unroll
      for (int m = 0; m < 4; ++m) a2[m] = v4f{0, 0, 0, 0};
      const unsigned char* b1p = &hb1[(t + 1) & 1][0];  // h1(t-1)
      __builtin_amdgcn_s_setprio(1);
#pragma unroll
      for (int kt = 0; kt < 4; ++kt) {
        v8h b2 = *(const v8h*)(hb2 + kt * FB_KT + roff);  // h2(t-2)
        v8h b1 = *(const v8h*)(b1p + kt * FB_KT + roff);
#pragma unroll
        for (int m = 0; m < 4; ++m) {
          a2[m] = MFMA16(A2hf[m][kt], b2, a2[m]);
          a2[m] = MFMA16(A2if[m][kt], b1, a2[m]);
        }
      }
      __builtin_amdgcn_s_setprio(0);
      if (m15 < 2) {
#pragma unroll
        for (int m = 0; m < 4; ++m)
          *(v4f*)&gbuf2[m15][(4 * wv + m) * 16 + quad * 4] = a2[m];
      }
    }
    __syncthreads();

    // ===== SegB: U2(t-1) [wv2-3] || C-B: gbuf1 = A1@h1(t) =====
    if (tid >= 128 && tid < 256 && t > 0) {
      const int row = (tid >> 6) & 1;
      const float* g2 = gbuf2[row];
      float2 gi = *(const float2*)&g2[e];
      float2 gf = *(const float2*)&g2[128 + e];
      float2 gg = *(const float2*)&g2[256 + e];
      float2 go = *(const float2*)&g2[384 + e];
      float2 bi = *(const float2*)&bbb2[e];
      float2 bf = *(const float2*)&bbb2[128 + e];
      float2 bg = *(const float2*)&bbb2[256 + e];
      float2 bo = *(const float2*)&bbb2[384 + e];
      float i0 = sigmoid_f(gi.x + bi.x);
      float i1 = sigmoid_f(gi.y + bi.y);
      float f0 = sigmoid_f(gf.x + bf.x);
      float f1 = sigmoid_f(gf.y + bf.y);
      float g0 = tanh_f(gg.x + bg.x);
      float g1v = tanh_f(gg.y + bg.y);
      float o0 = sigmoid_f(go.x + bo.x);
      float o1 = sigmoid_f(go.y + bo.y);
      c2x = f0 * c2x + i0 * g0;
      c2y = f1 * c2y + i1 * g1v;
      float h0 = o0 * tanh_f(c2x);
      float h1 = o1 * tanh_f(c2y);
      h2t hp = h2t{(_Float16)h0, (_Float16)h1};
      *(unsigned*)(hb2 + row * 16 + hwo) = __builtin_bit_cast(unsigned, hp);
      float2 wlv = *(const float2*)&wlb[e];
      float p2 = h0 * wlv.x + h1 * wlv.y;
#pragma unroll
      for (int s = 1; s < 64; s <<= 1) p2 += __shfl_xor(p2, s, 64);
      if (lane == 0) olds[row * L_ + (t - 1)] = p2 + blv;
    }
    if (t < L_) {  // C-B: all 8 waves, 16 MFMA each
      v4f a1[4];
#pragma unroll
      for (int m = 0; m < 4; ++m) a1[m] = v4f{0, 0, 0, 0};
      const unsigned char* b1p = &hb1[t & 1][0];  // h1(t)
      __builtin_amdgcn_s_setprio(1);
#pragma unroll
      for (int kt = 0; kt < 4; ++kt) {
        v8h b1 = *(const v8h*)(b1p + kt * FB_KT + roff);
#pragma unroll
        for (int m = 0; m < 4; ++m) a1[m] = MFMA16(A1f[m][kt], b1, a1[m]);
      }
      __builtin_amdgcn_s_setprio(0);
      if (m15 < 2) {
#pragma unroll
        for (int m = 0; m < 4; ++m)
          *(v4f*)&gbuf1[m15][(4 * wv + m) * 16 + quad * 4] = a1[m];
      }
    }
    __syncthreads();
  }

  // ---- one-shot coalesced flush of staged outputs ----
  for (int i = tid; i < 2 * L_; i += 512) out[r0 * L_ + i] = olds[i];
}

extern "C" void kernel_launch(void* const* d_in, const int* in_sizes, int n_in,
                              void* d_out, int out_size, void* d_ws, size_t ws_size,
                              hipStream_t stream) {
  const float* x     = (const float*)d_in[0];
  const float* w_ih1 = (const float*)d_in[1];
  const float* w_hh1 = (const float*)d_in[2];
  const float* b_ih1 = (const float*)d_in[3];
  const float* b_hh1 = (const float*)d_in[4];
  const float* w_ih2 = (const float*)d_in[5];
  const float* w_hh2 = (const float*)d_in[6];
  const float* b_ih2 = (const float*)d_in[7];
  const float* b_hh2 = (const float*)d_in[8];
  const float* w_lin = (const float*)d_in[9];
  const float* b_lin = (const float*)d_in[10];

  lstm_mfma<<<B_ / 2, 512, 0, stream>>>(
      x, w_ih1, w_hh1, b_ih1, b_hh1, w_ih2, w_hh2, b_ih2, b_hh2,
      w_lin, b_lin, (float*)d_out);
}